// Round 3
// baseline (73.951 us; speedup 1.0000x reference)
//
#include <hip/hip_runtime.h>

// ConvCapsules2d:
//  activations: [8,32,14,14] f32
//  poses:       [8,32,4,4,14,14] f32
//  W_ij:        [32,32,4,4,3,3] f32  (b,c,m,j,k,l)
// Outputs (concatenated flat):
//  acts_out: [8,32,6,6,3,3]                  = 82944 f32
//  V_ji:     [8,32,32,16,6,6,3,3]            = 42467328 f32
// V[n,b,c,i,j,f,g,k,l] = sum_m poses[n,b,i,m,f*2+k,g*2+l] * W[b,c,m,j,k,l]
// patch flat index r = f*54 + g*9 + k*3 + l ; wo(r) = r%9 ; po(r) below

#define RLEN 324
#define ACTS_OUT 82944
#define PR_ELEMS (256 * RLEN * 16)      // 1,327,104 floats: Pr[nb][r][i*4+m]
#define WR_ELEMS (1024 * RLEN * 16)     // 5,308,416 floats: Wr[bc][r][m*4+j]
#define WS_NEEDED ((size_t)(PR_ELEMS + WR_ELEMS) * 4)

__device__ __forceinline__ int po_of(int r) {
    int f = r / 54;  int r1 = r - f * 54;
    int g = r1 / 9;  int r2 = r1 - g * 9;
    int k = r2 / 3;  int l  = r2 - k * 3;
    return (f * 2 + k) * 14 + (g * 2 + l);
}

// ---------------- fast path ----------------

__global__ __launch_bounds__(256) void prep_all(const float* __restrict__ act,
                                                const float* __restrict__ poses,
                                                const float* __restrict__ W,
                                                float* __restrict__ out,
                                                float* __restrict__ ws) {
    const int total = PR_ELEMS + WR_ELEMS + ACTS_OUT;
    for (int e = blockIdx.x * 256 + threadIdx.x; e < total; e += gridDim.x * 256) {
        if (e < PR_ELEMS) {
            int im = e & 15;
            int t  = e >> 4;
            int r  = t % RLEN;
            int nb = t / RLEN;
            ws[e] = poses[nb * 3136 + im * 196 + po_of(r)];
        } else if (e < PR_ELEMS + WR_ELEMS) {
            int e2 = e - PR_ELEMS;
            int mj = e2 & 15;
            int t  = e2 >> 4;
            int r  = t % RLEN;
            int bc = t / RLEN;
            int m = mj >> 2, j = mj & 3;
            ws[e] = W[bc * 144 + m * 36 + j * 9 + (r % 9)];
        } else {
            int a  = e - PR_ELEMS - WR_ELEMS;
            int nb = a / RLEN;
            int r  = a - nb * RLEN;
            out[a] = act[nb * 196 + po_of(r)];
        }
    }
}

__global__ __launch_bounds__(256) void v2_kernel(const float* __restrict__ ws,
                                                 float* __restrict__ out) {
    const int bid = blockIdx.x;            // n*1024 + b*32 + c
    const int bc  = bid & 1023;            // b*32 + c
    const int nb  = bid >> 5;              // n*32 + b
    const float4* __restrict__ Pr = (const float4*)ws + (size_t)nb * (RLEN * 4);
    const float4* __restrict__ Wr = (const float4*)(ws + PR_ELEMS) + (size_t)bc * (RLEN * 4);
    float* __restrict__ obase = out + ACTS_OUT + (size_t)bid * 5184;

    for (int r = threadIdx.x; r < RLEN; r += 256) {
        const float4* prow = Pr + r * 4;
        const float4* wrow = Wr + r * 4;
        float4 p0 = prow[0], p1 = prow[1], p2 = prow[2], p3 = prow[3]; // p_i = (m0..m3)
        float4 w0 = wrow[0], w1 = wrow[1], w2 = wrow[2], w3 = wrow[3]; // w_m = (j0..j3)
        #pragma unroll
        for (int i = 0; i < 4; ++i) {
            float4 pi = (i == 0) ? p0 : (i == 1) ? p1 : (i == 2) ? p2 : p3;
            float4 v;
            v.x = pi.x * w0.x + pi.y * w1.x + pi.z * w2.x + pi.w * w3.x;
            v.y = pi.x * w0.y + pi.y * w1.y + pi.z * w2.y + pi.w * w3.y;
            v.z = pi.x * w0.z + pi.y * w1.z + pi.z * w2.z + pi.w * w3.z;
            v.w = pi.x * w0.w + pi.y * w1.w + pi.z * w2.w + pi.w * w3.w;
            obase[(i * 4 + 0) * RLEN + r] = v.x;
            obase[(i * 4 + 1) * RLEN + r] = v.y;
            obase[(i * 4 + 2) * RLEN + r] = v.z;
            obase[(i * 4 + 3) * RLEN + r] = v.w;
        }
    }
}

// ---------------- fallback path (known-good, 58 µs) ----------------

__global__ __launch_bounds__(256) void acts_kernel(const float* __restrict__ act,
                                                   float* __restrict__ out) {
    int a = blockIdx.x * 256 + threadIdx.x;
    int nb = a / RLEN;
    int r  = a - nb * RLEN;
    out[a] = act[nb * 196 + po_of(r)];
}

__global__ __launch_bounds__(256) void v_kernel(const float* __restrict__ poses,
                                                const float* __restrict__ W,
                                                float* __restrict__ out) {
    __shared__ float Pl[3136];
    __shared__ float Wl[144];
    __shared__ int   poseOff[RLEN];
    __shared__ int   wOff[RLEN];

    const int bid = blockIdx.x;
    const int c   = bid & 31;
    const int b   = (bid >> 5) & 31;
    const int nb  = bid >> 5;
    const int tid = threadIdx.x;

    const float4* psrc = (const float4*)(poses + (size_t)nb * 3136);
    for (int i4 = tid; i4 < 784; i4 += 256)
        ((float4*)Pl)[i4] = psrc[i4];
    const float4* wsrc = (const float4*)(W + (size_t)(b * 32 + c) * 144);
    if (tid < 36) ((float4*)Wl)[tid] = wsrc[tid];
    for (int r = tid; r < RLEN; r += 256) {
        poseOff[r] = po_of(r);
        wOff[r]    = r % 9;
    }
    __syncthreads();

    float* obase = out + ACTS_OUT + (size_t)bid * 5184;
    for (int idx4 = tid; idx4 < 1296; idx4 += 256) {
        int ij = idx4 / 81;
        int rb = (idx4 - ij * 81) * 4;
        int i = ij >> 2, j = ij & 3;
        const float* Pi = Pl + i * 784;
        const float* Wj = Wl + j * 9;
        float vv[4];
        #pragma unroll
        for (int e = 0; e < 4; ++e) {
            int r  = rb + e;
            int po = poseOff[r];
            int wo = wOff[r];
            float acc = 0.f;
            #pragma unroll
            for (int m = 0; m < 4; ++m)
                acc += Pi[m * 196 + po] * Wj[m * 36 + wo];
            vv[e] = acc;
        }
        *((float4*)(obase + ij * 324 + rb)) = make_float4(vv[0], vv[1], vv[2], vv[3]);
    }
}

extern "C" void kernel_launch(void* const* d_in, const int* in_sizes, int n_in,
                              void* d_out, int out_size, void* d_ws, size_t ws_size,
                              hipStream_t stream) {
    const float* act   = (const float*)d_in[0];
    const float* poses = (const float*)d_in[1];
    const float* W     = (const float*)d_in[2];
    float* out = (float*)d_out;

    if (ws_size >= WS_NEEDED) {
        float* ws = (float*)d_ws;
        prep_all<<<8192, 256, 0, stream>>>(act, poses, W, out, ws);
        v2_kernel<<<8192, 256, 0, stream>>>(ws, out);
    } else {
        acts_kernel<<<324, 256, 0, stream>>>(act, out);
        v_kernel<<<8192, 256, 0, stream>>>(poses, W, out);
    }
}

// Round 4
// 40.083 us; speedup vs baseline: 1.8449x; 1.8449x over previous
//
#include <hip/hip_runtime.h>

// ConvCapsules2d:
//  activations: [8,32,14,14] f32
//  poses:       [8,32,4,4,14,14] f32
//  W_ij:        [32,32,4,4,3,3] f32  (b,c,m,j,k,l)
// Outputs (concatenated flat):
//  acts_out: [8,32,6,6,3,3]                  = 82944 f32
//  V_ji:     [8,32,32,16,6,6,3,3]            = 42467328 f32
// V[n,b,c,i,j,f,g,k,l] = sum_m poses[n,b,i,m,f*2+k,g*2+l] * W[b,c,m,j,k,l]
// patch flat index r = f*54 + g*9 + k*3 + l ; wo(r) = r%9
// po(r) = (f*2+k)*14 + (g*2+l)

#define RLEN 324
#define ACTS_OUT 82944

__device__ __forceinline__ int po_of(int r) {
    int f = r / 54;  int r1 = r - f * 54;
    int g = r1 / 9;  int r2 = r1 - g * 9;
    int k = r2 / 3;  int l  = r2 - k * 3;
    return (f * 2 + k) * 14 + (g * 2 + l);
}

__global__ __launch_bounds__(256) void acts_kernel(const float* __restrict__ act,
                                                   float* __restrict__ out) {
    int a = blockIdx.x * 256 + threadIdx.x;   // < 82944 = 324*256
    int nb = a / RLEN;
    int r  = a - nb * RLEN;
    out[a] = act[nb * 196 + po_of(r)];
}

// One thread = one patch position r; computes all 16 (i,j) outputs in regs.
// 32 ds_read_b32 per 16 outputs (vs 10 per output in the round-2 kernel).
__global__ __launch_bounds__(384) void v3_kernel(const float* __restrict__ poses,
                                                 const float* __restrict__ W,
                                                 float* __restrict__ out) {
    __shared__ float Pl[3136];   // poses[n,b]: (i*4+m)*196 + h*14+w
    __shared__ float Wl[144];    // W[b,c]:     m*36 + j*9 + wo

    const int bid = blockIdx.x;          // n*1024 + b*32 + c
    const int bc  = bid & 1023;          // b*32 + c
    const int nb  = bid >> 5;            // n*32 + b
    const int tid = threadIdx.x;

    // stage poses[n,b]: 784 float4 across 384 threads
    const float4* psrc = (const float4*)(poses + (size_t)nb * 3136);
    for (int i4 = tid; i4 < 784; i4 += 384)
        ((float4*)Pl)[i4] = psrc[i4];
    // stage W[b,c]: 36 float4
    const float4* wsrc = (const float4*)(W + (size_t)bc * 144);
    if (tid < 36) ((float4*)Wl)[tid] = wsrc[tid];
    __syncthreads();

    if (tid < RLEN) {
        const int r  = tid;
        const int po = po_of(r);         // in regs; no table
        const int wo = r % 9;

        // P fragment: 16 reads, one vaddr (po*4) + immediate offsets
        float p[4][4];
        #pragma unroll
        for (int i = 0; i < 4; ++i)
            #pragma unroll
            for (int m = 0; m < 4; ++m)
                p[i][m] = Pl[(i * 4 + m) * 196 + po];

        // W fragment: 16 reads, one vaddr (wo*4) + immediate offsets;
        // only 9 distinct wo per wave -> mostly broadcast
        float w[4][4];
        #pragma unroll
        for (int m = 0; m < 4; ++m)
            #pragma unroll
            for (int j = 0; j < 4; ++j)
                w[m][j] = Wl[m * 36 + j * 9 + wo];

        float* obase = out + ACTS_OUT + (size_t)bid * 5184 + r;
        #pragma unroll
        for (int i = 0; i < 4; ++i) {
            #pragma unroll
            for (int j = 0; j < 4; ++j) {
                float acc = p[i][0] * w[0][j] + p[i][1] * w[1][j]
                          + p[i][2] * w[2][j] + p[i][3] * w[3][j];
                obase[(i * 4 + j) * RLEN] = acc;   // lanes = consecutive r: coalesced
            }
        }
    }
}

extern "C" void kernel_launch(void* const* d_in, const int* in_sizes, int n_in,
                              void* d_out, int out_size, void* d_ws, size_t ws_size,
                              hipStream_t stream) {
    const float* act   = (const float*)d_in[0];
    const float* poses = (const float*)d_in[1];
    const float* W     = (const float*)d_in[2];
    float* out = (float*)d_out;

    acts_kernel<<<324, 256, 0, stream>>>(act, out);
    v3_kernel<<<8192, 384, 0, stream>>>(poses, W, out);
}

// Round 5
// 35.483 us; speedup vs baseline: 2.0841x; 1.1296x over previous
//
#include <hip/hip_runtime.h>

// ConvCapsules2d:
//  activations: [8,32,14,14] f32
//  poses:       [8,32,4,4,14,14] f32
//  W_ij:        [32,32,4,4,3,3] f32  (b,c,m,j,k,l)
// Outputs (concatenated flat):
//  acts_out: [8,32,6,6,3,3]                  = 82944 f32
//  V_ji:     [8,32,32,16,6,6,3,3]            = 42467328 f32
// V[n,b,c,i,j,f,g,k,l] = sum_m poses[n,b,i,m,f*2+k,g*2+l] * W[b,c,m,j,k,l]
// r = f*54 + g*9 + k*3 + l ; wo(r) = r%9 ; po(r) = (f*2+k)*14 + (g*2+l)

#define RLEN 324
#define ACTS_OUT 82944
#define PSTRIDE 20   // dwords per row: 16 data + 4 pad; 80 B (16B-aligned, bank-spread)

__device__ __forceinline__ int po_of(int r) {
    int f = r / 54;  int r1 = r - f * 54;
    int g = r1 / 9;  int r2 = r1 - g * 9;
    int k = r2 / 3;  int l  = r2 - k * 3;
    return (f * 2 + k) * 14 + (g * 2 + l);
}

// One block per (n,b,c). Transposed LDS: Pl2[po][i*4+m], Wl2[wo][m*4+j],
// row stride 20 dwords -> fragment loads are 4+4 ds_read_b128, conflict-free.
__global__ __launch_bounds__(384) void v4_kernel(const float* __restrict__ act,
                                                 const float* __restrict__ poses,
                                                 const float* __restrict__ W,
                                                 float* __restrict__ out) {
    __shared__ float Pl2[196 * PSTRIDE];   // 15.7 KB
    __shared__ float Wl2[9 * PSTRIDE];     // 720 B

    const int bid = blockIdx.x;            // n*1024 + b*32 + c
    const int bc  = bid & 1023;
    const int nb  = bid >> 5;
    const int tid = threadIdx.x;

    // ---- stage poses[n,b] transposed: Pl2[po*20 + i*4+m] = poses[nb][i][m][po]
    // lanes: consecutive t -> consecutive po (same i) -> 4 coalesced dword
    // streams from L2; each thread writes one 16B row-chunk (b128, bank-spread).
    const float* pn = poses + (size_t)nb * 3136;
    for (int t = tid; t < 784; t += 384) {
        int i  = t / 196;
        int po = t - i * 196;
        float4 v;
        v.x = pn[(i * 4 + 0) * 196 + po];
        v.y = pn[(i * 4 + 1) * 196 + po];
        v.z = pn[(i * 4 + 2) * 196 + po];
        v.w = pn[(i * 4 + 3) * 196 + po];
        *(float4*)&Pl2[po * PSTRIDE + i * 4] = v;
    }
    // ---- stage W[b,c] transposed: Wl2[wo*20 + m*4+j] = W[bc][m][j][wo]
    if (tid < 36) {
        int wo = tid / 4, m = tid & 3;
        const float* wb = W + (size_t)bc * 144 + m * 36 + wo;
        float4 v;
        v.x = wb[0 * 9];
        v.y = wb[1 * 9];
        v.z = wb[2 * 9];
        v.w = wb[3 * 9];
        *(float4*)&Wl2[wo * PSTRIDE + m * 4] = v;
    }
    __syncthreads();

    if (tid < RLEN) {
        const int r  = tid;
        const int po = po_of(r);
        const int wo = r % 9;

        float4 p0 = *(const float4*)&Pl2[po * PSTRIDE + 0];   // i=0, m0..3
        float4 p1 = *(const float4*)&Pl2[po * PSTRIDE + 4];
        float4 p2 = *(const float4*)&Pl2[po * PSTRIDE + 8];
        float4 p3 = *(const float4*)&Pl2[po * PSTRIDE + 12];
        float4 w0 = *(const float4*)&Wl2[wo * PSTRIDE + 0];   // m=0, j0..3
        float4 w1 = *(const float4*)&Wl2[wo * PSTRIDE + 4];
        float4 w2 = *(const float4*)&Wl2[wo * PSTRIDE + 8];
        float4 w3 = *(const float4*)&Wl2[wo * PSTRIDE + 12];

        float* obase = out + ACTS_OUT + (size_t)bid * 5184 + r;
        #pragma unroll
        for (int i = 0; i < 4; ++i) {
            float4 pi = (i == 0) ? p0 : (i == 1) ? p1 : (i == 2) ? p2 : p3;
            float4 v;
            v.x = pi.x * w0.x + pi.y * w1.x + pi.z * w2.x + pi.w * w3.x;
            v.y = pi.x * w0.y + pi.y * w1.y + pi.z * w2.y + pi.w * w3.y;
            v.z = pi.x * w0.z + pi.y * w1.z + pi.z * w2.z + pi.w * w3.z;
            v.w = pi.x * w0.w + pi.y * w1.w + pi.z * w2.w + pi.w * w3.w;
            obase[(i * 4 + 0) * RLEN] = v.x;
            obase[(i * 4 + 1) * RLEN] = v.y;
            obase[(i * 4 + 2) * RLEN] = v.z;
            obase[(i * 4 + 3) * RLEN] = v.w;
        }

        // fused acts_out gather: only the c==0 block of each (n,b) does it
        if ((bid & 31) == 0)
            out[nb * RLEN + r] = act[nb * 196 + po];
    }
}

extern "C" void kernel_launch(void* const* d_in, const int* in_sizes, int n_in,
                              void* d_out, int out_size, void* d_ws, size_t ws_size,
                              hipStream_t stream) {
    const float* act   = (const float*)d_in[0];
    const float* poses = (const float*)d_in[1];
    const float* W     = (const float*)d_in[2];
    float* out = (float*)d_out;

    v4_kernel<<<8192, 384, 0, stream>>>(act, poses, W, out);
}